// Round 1
// baseline (76.635 us; speedup 1.0000x reference)
//
#include <hip/hip_runtime.h>

// Problem constants (from reference)
#define B_   8
#define CIN_ 4
#define H_   64
#define W_   64
#define OUT_ 8
#define K_   3
#define K2_  9
#define G_   8
#define HO_  62
#define WO_  62
#define P_   (HO_ * WO_)      // 3844
#define R_   6.25f            // 4*25/16
#define PBLK ((P_ + 255) / 256)  // 16 pixel-chunks of 256

__global__ __launch_bounds__(256) void kan_conv_kernel(
    const float* __restrict__ x,       // [B, CIN, H, W]
    const float* __restrict__ pl,      // [OUT, CIN, K2, G]
    const float* __restrict__ ph,      // [OUT, CIN, K2, G]
    const float* __restrict__ w,       // [OUT, CIN, K2, G]
    const float* __restrict__ bias,    // [OUT, CIN]
    float* __restrict__ out)           // [B, OUT, HO, WO]
{
    // block → (b, o, pixel-chunk)
    int bid  = blockIdx.x;
    int pblk = bid % PBLK;
    int bo   = bid / PBLK;
    int o    = bo % OUT_;
    int b    = bo / OUT_;

    // Stage this o's weight (with R^2 folded in) and phases into LDS.
    __shared__ float s_w [CIN_ * K2_ * G_];   // 288 floats
    __shared__ float s_pl[CIN_ * K2_ * G_];
    __shared__ float s_ph[CIN_ * K2_ * G_];

    const int t = threadIdx.x;
    const int obase = o * CIN_ * K2_ * G_;
    for (int i = t; i < CIN_ * K2_ * G_; i += 256) {
        s_w [i] = w [obase + i] * (R_ * R_);
        s_pl[i] = pl[obase + i];
        s_ph[i] = ph[obase + i];
    }
    __syncthreads();

    const int p = pblk * 256 + t;
    if (p >= P_) return;
    const int oy = p / WO_;
    const int ox = p - oy * WO_;

    float acc = 0.0f;
    #pragma unroll
    for (int c = 0; c < CIN_; ++c) {
        const float* xc = x + ((size_t)(b * CIN_ + c)) * H_ * W_;
        #pragma unroll
        for (int ki = 0; ki < K_; ++ki) {
            #pragma unroll
            for (int kj = 0; kj < K_; ++kj) {
                const float xv = xc[(oy + ki) * W_ + (ox + kj)];
                const int base = (c * K2_ + (ki * K_ + kj)) * G_;
                #pragma unroll
                for (int g = 0; g < G_; ++g) {
                    // lane-uniform LDS address → broadcast, no bank conflicts
                    const float d1 = xv - s_pl[base + g];
                    const float d2 = s_ph[base + g] - xv;
                    const float u  = fmaxf(d1, 0.0f) * fmaxf(d2, 0.0f);
                    acc = fmaf(u * u, s_w[base + g], acc);
                }
            }
        }
    }

    // + bias.sum(axis=1)[o]
    float bs = 0.0f;
    #pragma unroll
    for (int c = 0; c < CIN_; ++c) bs += bias[o * CIN_ + c];

    out[((size_t)(b * OUT_ + o)) * P_ + p] = acc + bs;
}

extern "C" void kernel_launch(void* const* d_in, const int* in_sizes, int n_in,
                              void* d_out, int out_size, void* d_ws, size_t ws_size,
                              hipStream_t stream) {
    const float* x    = (const float*)d_in[0];
    const float* pl   = (const float*)d_in[1];
    const float* ph   = (const float*)d_in[2];
    const float* w    = (const float*)d_in[3];
    const float* bias = (const float*)d_in[4];
    float* out = (float*)d_out;

    const int grid = B_ * OUT_ * PBLK;  // 8*8*16 = 1024 blocks
    kan_conv_kernel<<<grid, 256, 0, stream>>>(x, pl, ph, w, bias, out);
}